// Round 2
// baseline (177.801 us; speedup 1.0000x reference)
//
#include <hip/hip_runtime.h>
#include <hip/hip_bf16.h>
#include <stdint.h>

#define B_DIM   4096
#define IN_DIM  512
#define OUT_DIM 512
#define M_DIM   16
#define K_DIM   (IN_DIM * M_DIM)     // 8192
#define MN      (B_DIM * OUT_DIM)    // 2097152

typedef unsigned short ushort_t;
typedef __attribute__((ext_vector_type(8))) __bf16 bf16x8;
typedef __attribute__((ext_vector_type(4))) float  f32x4;

__device__ __forceinline__ ushort_t f2bf(float f) {
  union { float f; uint32_t u; } v; v.f = f;
  uint32_t u = v.u + 0x7fffu + ((v.u >> 16) & 1u);   // RNE
  return (ushort_t)(u >> 16);
}

// ---------- phase 1a: coeffs fp32 -> bf16 (layout [OUT][IN][M] == B^T [N][K]) ----------
__global__ __launch_bounds__(256) void convert_coeffs_kernel(
    const float* __restrict__ src, ushort_t* __restrict__ dst, int n4) {
  int i = blockIdx.x * 256 + threadIdx.x;
  if (i >= n4) return;
  float4 v = ((const float4*)src)[i];
  ushort4 o;
  o.x = f2bf(v.x); o.y = f2bf(v.y); o.z = f2bf(v.z); o.w = f2bf(v.w);
  ((ushort4*)dst)[i] = o;
}

// ---------- phase 1b: basis bf16 [B_DIM][IN_DIM*M_DIM], K index = i*16+m ----------
// 2 x-values per thread: interleaved transcendental chains for ILP, 64B store.
__global__ __launch_bounds__(256, 1) void basis_kernel(
    const float* __restrict__ x, const float* __restrict__ bc,
    ushort_t* __restrict__ basis) {
  int idx2 = blockIdx.x * 256 + threadIdx.x;     // pair index, 1M threads
  float2 xp = ((const float2*)x)[idx2];
  float x0 = xp.x, x1 = xp.y;
  float p0_2 = x0 * x0, p0_3 = p0_2 * x0, p0_4 = p0_2 * p0_2;
  float p1_2 = x1 * x1, p1_3 = p1_2 * x1, p1_4 = p1_2 * p1_2;
  const float LOG2E = 1.44269504088896340736f;
  const float LN2   = 0.69314718055994530942f;
  uint32_t w0[8], w1[8];
  #pragma unroll
  for (int m = 0; m < 16; ++m) {
    float b1 = bc[m*8+0], b2 = bc[m*8+1], b3 = bc[m*8+2], b4 = bc[m*8+3];
    float b5 = bc[m*8+4], b6 = bc[m*8+5], b7 = bc[m*8+6], b8 = bc[m*8+7];
    // two independent chains, interleaved
    float e0 = __builtin_amdgcn_exp2f(b3 * x0 * LOG2E);
    float e1 = __builtin_amdgcn_exp2f(b3 * x1 * LOG2E);
    float l0 = __builtin_amdgcn_logf(e0 - 1.0f);
    float l1 = __builtin_amdgcn_logf(e1 - 1.0f);
    float q0 = __builtin_amdgcn_exp2f(b4 * l0);
    float q1 = __builtin_amdgcn_exp2f(b4 * l1);
    float u0 = LN2 * __builtin_amdgcn_logf(1.0f + q0);
    float u1 = LN2 * __builtin_amdgcn_logf(1.0f + q1);
    float v0 = LN2 * __builtin_amdgcn_logf(1.0f + b2 * u0);
    float v1 = LN2 * __builtin_amdgcn_logf(1.0f + b2 * u1);
    float y0 = b1 * v0 + b5 * x0 + b6 * p0_2 + b7 * p0_3 + b8 * p0_4;
    float y1 = b1 * v1 + b5 * x1 + b6 * p1_2 + b7 * p1_3 + b8 * p1_4;
    uint32_t h0 = (uint32_t)f2bf(y0);
    uint32_t h1 = (uint32_t)f2bf(y1);
    if (m & 1) { w0[m >> 1] |= (h0 << 16); w1[m >> 1] |= (h1 << 16); }
    else       { w0[m >> 1] = h0;          w1[m >> 1] = h1; }
  }
  uint4* dst = (uint4*)(basis + (size_t)idx2 * 32);   // 64B contiguous per thread
  dst[0] = make_uint4(w0[0], w0[1], w0[2], w0[3]);
  dst[1] = make_uint4(w0[4], w0[5], w0[6], w0[7]);
  dst[2] = make_uint4(w1[0], w1[1], w1[2], w1[3]);
  dst[3] = make_uint4(w1[4], w1[5], w1[6], w1[7]);
}

// ---------- phase 2: GEMM C[M][N] = A[M][K] * Bt[N][K]^T, split-K ----------
// LDS tiles stored in MFMA-FRAGMENT ORDER: per 16-row group g, chunk c = koct*16 + row
// holds rows[g*16+row], k[koct*8 .. +8). Fragment ds_read = base + lane*16: conflict-free,
// and matches global_load_lds's fixed "uniform base + lane*16" placement exactly.
#define BM 128
#define BN 128
#define BK 32
#define SPLITK 8
#define KC (K_DIM / SPLITK)   // 1024 per split -> 32 K-iterations

#define GLD16(g, l) \
  __builtin_amdgcn_global_load_lds((const __attribute__((address_space(1))) void*)(g), \
                                   (__attribute__((address_space(3))) void*)(l), 16, 0, 0)

template <int ATOMIC>
__global__ __launch_bounds__(256, 2) void gemm_kernel(
    const ushort_t* __restrict__ A,   // basis [B_DIM][K_DIM] bf16
    const ushort_t* __restrict__ Bt,  // coeffs [OUT_DIM][K_DIM] bf16
    float* __restrict__ P) {          // partials [SPLITK][B_DIM][OUT_DIM] or out
  __shared__ __align__(16) ushort_t As[BM * BK];   // 8 groups x 512 ushorts
  __shared__ __align__(16) ushort_t Bs[BN * BK];
  const int tid  = threadIdx.x;
  const int wave = tid >> 6;
  const int lane = tid & 63;
  const int bm = blockIdx.x, bn = blockIdx.y, ks = blockIdx.z;

  // staging in fragment order: lane i fetches chunk i of its group:
  //   row-in-group = i & 15, k-octet = i >> 4
  const int grow = lane & 15;
  const int koct = lane >> 4;
  const int g0 = 2 * wave, g1 = 2 * wave + 1;
  const ushort_t* Ag0 = A  + (size_t)(bm * BM + g0 * 16 + grow) * K_DIM + (size_t)ks * KC + koct * 8;
  const ushort_t* Ag1 = A  + (size_t)(bm * BM + g1 * 16 + grow) * K_DIM + (size_t)ks * KC + koct * 8;
  const ushort_t* Bg0 = Bt + (size_t)(bn * BN + g0 * 16 + grow) * K_DIM + (size_t)ks * KC + koct * 8;
  const ushort_t* Bg1 = Bt + (size_t)(bn * BN + g1 * 16 + grow) * K_DIM + (size_t)ks * KC + koct * 8;
  ushort_t* AsW0 = As + g0 * 512;   // wave-uniform LDS base; HW adds lane*16B
  ushort_t* AsW1 = As + g1 * 512;
  ushort_t* BsW0 = Bs + g0 * 512;
  ushort_t* BsW1 = Bs + g1 * 512;

  // 2x2 wave grid; each wave computes 64x64 via 4x4 tiles of 16x16x32 MFMA
  const int wr = wave >> 1, wc = wave & 1;
  const int fm = lane & 15;

  f32x4 acc[4][4] = {};

  for (int kt = 0; kt < KC; kt += BK) {
    GLD16(Ag0, AsW0); GLD16(Ag1, AsW1);
    GLD16(Bg0, BsW0); GLD16(Bg1, BsW1);
    Ag0 += BK; Ag1 += BK; Bg0 += BK; Bg1 += BK;
    __syncthreads();   // drains vmcnt (global_load_lds)
    bf16x8 af[4], bfv[4];
    #pragma unroll
    for (int t = 0; t < 4; ++t) {
      af[t]  = *(const bf16x8*)(As + (wr * 4 + t) * 512 + lane * 8);  // base + lane*16B
      bfv[t] = *(const bf16x8*)(Bs + (wc * 4 + t) * 512 + lane * 8);
    }
    #pragma unroll
    for (int mt = 0; mt < 4; ++mt)
      #pragma unroll
      for (int nt = 0; nt < 4; ++nt)
        acc[mt][nt] = __builtin_amdgcn_mfma_f32_16x16x32_bf16(af[mt], bfv[nt], acc[mt][nt], 0, 0, 0);
    __syncthreads();
  }

  // epilogue: C/D layout col = lane&15, row = (lane>>4)*4 + reg
  const int colb = bn * BN + wc * 64 + fm;
  const int rowb = bm * BM + wr * 64 + (lane >> 4) * 4;
  float* out = P + (ATOMIC ? (size_t)0 : (size_t)ks * MN);
  #pragma unroll
  for (int mt = 0; mt < 4; ++mt) {
    #pragma unroll
    for (int nt = 0; nt < 4; ++nt) {
      #pragma unroll
      for (int j = 0; j < 4; ++j) {
        int row = rowb + mt * 16 + j;
        int col = colb + nt * 16;
        float vv = acc[mt][nt][j];
        if (ATOMIC) atomicAdd(out + (size_t)row * OUT_DIM + col, vv);
        else        out[(size_t)row * OUT_DIM + col] = vv;
      }
    }
  }
}

// ---------- phase 3: reduce split-K partials ----------
__global__ __launch_bounds__(256) void reduce_kernel(
    const float* __restrict__ P, float* __restrict__ out) {
  int i = blockIdx.x * 256 + threadIdx.x;   // MN/4 threads
  const float4* p = (const float4*)P;
  float4 r = p[i];
  #pragma unroll
  for (int s = 1; s < SPLITK; ++s) {
    float4 t = p[i + (size_t)s * (MN / 4)];
    r.x += t.x; r.y += t.y; r.z += t.z; r.w += t.w;
  }
  ((float4*)out)[i] = r;
}

extern "C" void kernel_launch(void* const* d_in, const int* in_sizes, int n_in,
                              void* d_out, int out_size, void* d_ws, size_t ws_size,
                              hipStream_t stream) {
  const float* x      = (const float*)d_in[0];   // [4096][512]
  const float* coeffs = (const float*)d_in[1];   // [512][512][16]
  const float* b_coef = (const float*)d_in[2];   // [16][8]
  float* out = (float*)d_out;
  char*  ws  = (char*)d_ws;

  const size_t BASIS_BYTES = (size_t)B_DIM * K_DIM * 2;     // 64 MiB
  const size_t COEF_BYTES  = (size_t)OUT_DIM * K_DIM * 2;   // 8 MiB
  ushort_t* basis = (ushort_t*)ws;
  ushort_t* coefb = (ushort_t*)(ws + BASIS_BYTES);
  float* partials = (float*)(ws + BASIS_BYTES + COEF_BYTES);
  const size_t FULL = BASIS_BYTES + COEF_BYTES + (size_t)SPLITK * MN * 4;
  const bool use_atomic = (ws_size < FULL);   // deterministic per-session branch

  convert_coeffs_kernel<<<(OUT_DIM * K_DIM / 4 + 255) / 256, 256, 0, stream>>>(
      coeffs, coefb, OUT_DIM * K_DIM / 4);
  basis_kernel<<<(B_DIM * IN_DIM / 2) / 256, 256, 0, stream>>>(x, b_coef, basis);

  dim3 grid(B_DIM / BM, OUT_DIM / BN, SPLITK);   // 32 x 4 x 8 = 1024 blocks
  if (use_atomic) {
    hipMemsetAsync(d_out, 0, (size_t)MN * 4, stream);
    gemm_kernel<1><<<grid, 256, 0, stream>>>(basis, coefb, out);
  } else {
    gemm_kernel<0><<<grid, 256, 0, stream>>>(basis, coefb, partials);
    reduce_kernel<<<MN / 4 / 256, 256, 0, stream>>>(partials, out);
  }
}